// Round 4
// baseline (177.841 us; speedup 1.0000x reference)
//
#include <hip/hip_runtime.h>
#include <math.h>

#define NEG_SLOPE 0.2f

typedef _Float16 half8 __attribute__((ext_vector_type(8)));
typedef float floatx4 __attribute__((ext_vector_type(4)));

__device__ __forceinline__ float dot4f(float4 a, float4 b) {
    return a.x * b.x + a.y * b.y + a.z * b.z + a.w * b.w;
}

static __device__ __forceinline__ unsigned short f2h(float x) {
    _Float16 h = (_Float16)x;               // RNE
    return __builtin_bit_cast(unsigned short, h);
}
static __device__ __forceinline__ float h2f(unsigned short u) {
    _Float16 h = __builtin_bit_cast(_Float16, u);
    return (float)h;
}

// ---------------------------------------------------------------------------
// Kernel 0: permute W -> Wtp fp16 in MFMA-B-fragment order:
// Wtp[cp][kc][cm][j] = fp16(W[kc*8+j][cp*16+cm]),  cp=col/16, kc=k/8.
// One-time 128 KB, L2-resident for the fused GEMM.
// ---------------------------------------------------------------------------
__global__ void k_prepw(const float* __restrict__ W, unsigned short* __restrict__ Wtp) {
    const int c = blockIdx.x;       // 256 cols
    const int k = threadIdx.x;      // 256 ks
    float v = W[(size_t)k * 256 + c];
    Wtp[(size_t)(c >> 4) * 4096 + (k >> 3) * 128 + (c & 15) * 8 + (k & 7)] = f2h(v);
}

// ---------------------------------------------------------------------------
// Kernel 1 (fused score + GEMM + el/er): block = 256 thr = 4 waves = 32 nodes
// = two MFMA A-panels (halves Wtp L2 traffic vs 16-row blocks).
// Phase A: per node y = |feat.p|/||p||, gate, gated fp16 row -> LDS.
// Phase B: 32x256 @ 256x256 matmul; wave w owns cols w*64..w*64+63;
//   A-frag = ds_read_b128 (A[m=l16][k=quad*8+j]), B-frag = coalesced 16B
//   global loads from Wtp. C/D: col=lane&15, row=quad*4+reg (m89/m91).
// Phase C: stage fp16 output panel back into LDS; 256 threads cooperatively
//   compute el[n,h]=ft[n,h,:].al[h,:] and er likewise (once per node — k_aggr
//   previously recomputed these 9x per node).
// ---------------------------------------------------------------------------
__global__ __launch_bounds__(256) void k_fused(const float4* __restrict__ feat4,
                                               const float4* __restrict__ p4,
                                               const unsigned short* __restrict__ Wtp,
                                               const float4* __restrict__ al4,
                                               const float4* __restrict__ ar4,
                                               float* __restrict__ y,
                                               unsigned short* __restrict__ fth,
                                               float* __restrict__ el,
                                               float* __restrict__ er,
                                               int N) {
    __shared__ unsigned short As[32][264];   // 32 rows x 256 halves (+pad)
    const int lane = threadIdx.x & 63;
    const int w = threadIdx.x >> 6;          // wave 0..3
    const int l16 = lane & 15, quad = lane >> 4;
    const int nb = blockIdx.x * 32;

    const float4 p = p4[lane];
    float pp = dot4f(p, p);
#pragma unroll
    for (int off = 32; off; off >>= 1) pp += __shfl_xor(pp, off, 64);
    const float rnorm = 1.0f / sqrtf(pp);

    // ---- phase A: 8 nodes per wave ----
#pragma unroll
    for (int j = 0; j < 8; ++j) {
        const int m = w * 8 + j;
        int n = nb + m;
        const bool valid = n < N;
        if (!valid) n = N - 1;
        float4 f = feat4[(size_t)n * 64 + lane];
        float dp = dot4f(f, p);
#pragma unroll
        for (int off = 32; off; off >>= 1) dp += __shfl_xor(dp, off, 64);
        float yv = fabsf(dp) * rnorm;
        if (lane == 0 && valid) y[n] = yv;
        float g = 2.0f / (1.0f + __expf(-yv));
        ushort4 u;
        u.x = f2h(g * f.x);
        u.y = f2h(g * f.y);
        u.z = f2h(g * f.z);
        u.w = f2h(g * f.w);
        *(ushort4*)&As[m][lane * 4] = u;
    }
    __syncthreads();

    // ---- phase B: 2 m-tiles x 4 col-tiles per wave ----
    floatx4 acc[2][4];
#pragma unroll
    for (int mt = 0; mt < 2; ++mt)
#pragma unroll
        for (int ct = 0; ct < 4; ++ct) acc[mt][ct] = (floatx4){0.f, 0.f, 0.f, 0.f};

    const unsigned short* bbase = Wtp + (size_t)(w * 4) * 4096 + quad * 128 + l16 * 8;

    for (int ks = 0; ks < 256; ks += 32) {
        half8 a0 = *(const half8*)&As[l16][ks + quad * 8];
        half8 a1 = *(const half8*)&As[16 + l16][ks + quad * 8];
        const unsigned short* bk = bbase + (ks >> 3) * 128;
        half8 b0 = *(const half8*)(bk);
        half8 b1 = *(const half8*)(bk + 4096);
        half8 b2 = *(const half8*)(bk + 8192);
        half8 b3 = *(const half8*)(bk + 12288);
        acc[0][0] = __builtin_amdgcn_mfma_f32_16x16x32_f16(a0, b0, acc[0][0], 0, 0, 0);
        acc[0][1] = __builtin_amdgcn_mfma_f32_16x16x32_f16(a0, b1, acc[0][1], 0, 0, 0);
        acc[0][2] = __builtin_amdgcn_mfma_f32_16x16x32_f16(a0, b2, acc[0][2], 0, 0, 0);
        acc[0][3] = __builtin_amdgcn_mfma_f32_16x16x32_f16(a0, b3, acc[0][3], 0, 0, 0);
        acc[1][0] = __builtin_amdgcn_mfma_f32_16x16x32_f16(a1, b0, acc[1][0], 0, 0, 0);
        acc[1][1] = __builtin_amdgcn_mfma_f32_16x16x32_f16(a1, b1, acc[1][1], 0, 0, 0);
        acc[1][2] = __builtin_amdgcn_mfma_f32_16x16x32_f16(a1, b2, acc[1][2], 0, 0, 0);
        acc[1][3] = __builtin_amdgcn_mfma_f32_16x16x32_f16(a1, b3, acc[1][3], 0, 0, 0);
    }

    // ---- epilogue: fth (global) + output panel back into As (LDS) ----
    __syncthreads();   // all A-frag reads done before overwrite
#pragma unroll
    for (int mt = 0; mt < 2; ++mt)
#pragma unroll
        for (int ct = 0; ct < 4; ++ct)
#pragma unroll
            for (int i = 0; i < 4; ++i) {
                int row = mt * 16 + quad * 4 + i;
                int col = w * 64 + ct * 16 + l16;
                unsigned short h = f2h(acc[mt][ct][i]);
                As[row][col] = h;
                int grow = nb + row;
                if (grow < N) fth[(size_t)grow * 256 + col] = h;
            }
    __syncthreads();

    // ---- phase C: el/er — 512 dot32 tasks over 256 threads ----
#pragma unroll
    for (int t2 = 0; t2 < 2; ++t2) {
        const int m = threadIdx.x & 31;        // node within panel
        const int h = (threadIdx.x >> 5) & 7;  // head
        const float4* att = t2 ? ar4 : al4;
        float d = 0.f;
#pragma unroll
        for (int o4 = 0; o4 < 8; ++o4) {
            ushort4 u = *(const ushort4*)&As[m][h * 32 + o4 * 4];
            float4 a = att[h * 8 + o4];
            d += h2f(u.x) * a.x + h2f(u.y) * a.y + h2f(u.z) * a.z + h2f(u.w) * a.w;
        }
        int n = nb + m;
        if (n < N) (t2 ? er : el)[(size_t)n * 8 + h] = d;
    }
}

// ---------------------------------------------------------------------------
// Kernel 2: per node — top-8 neighbors by y[src] via ballot radix-select
// (exact 8th-largest; tie -> lowest slot, matching jax.lax.top_k; selected
// SET is order-invariant under the symmetric softmax-sum), gather el[src]
// (precomputed) + fp16 ft rows, leaky-relu, softmax over k, weighted sum,
// elu. One wave per node; lane holds o-chunk 4*lane..4*lane+3, h = lane>>3.
// ---------------------------------------------------------------------------
__global__ __launch_bounds__(256) void k_aggr(const int* __restrict__ nbr,
                                              const float* __restrict__ y,
                                              const uint2* __restrict__ fth2,
                                              const float* __restrict__ el,
                                              const float* __restrict__ er,
                                              float4* __restrict__ out4,
                                              int N) {
    const int lane = threadIdx.x & 63;
    const int n = blockIdx.x * 4 + (threadIdx.x >> 6);
    if (n >= N) return;
    const int h = lane >> 3;

    const int s = nbr[(size_t)n * 64 + lane];
    const unsigned int key = __float_as_uint(y[s]);   // y >= 0 -> order-monotone

    // --- radix-select exact 8th-largest key (31 ballots; y>=0 so bit31=0) ---
    unsigned int t = 0u;
#pragma unroll
    for (int b = 30; b >= 0; --b) {
        unsigned int cand = t | (1u << b);
        unsigned long long m = __ballot(key >= cand);
        if (__popcll(m) >= 8) t = cand;
    }
    const unsigned long long gtmask = __ballot(key > t);
    const int ngt = __popcll(gtmask);                       // <= 7
    const unsigned long long eqmask = __ballot(key == t);
    const unsigned long long below = (1ull << lane) - 1ull;
    const int eqrank = __popcll(eqmask & below);
    const bool in8 = (key > t) | ((key == t) & (eqrank < 8 - ngt));
    unsigned long long selmask = __ballot(in8);             // exactly 8 bits

    int srck[8];
#pragma unroll
    for (int k = 0; k < 8; ++k) {
        int l = __ffsll((long long)selmask) - 1;
        srck[k] = __shfl(s, l, 64);
        selmask &= selmask - 1ull;
    }

    // --- gather fp16 ft rows (8B/lane, coalesced) + precomputed el ---
    float4 ftk[8];
#pragma unroll
    for (int k = 0; k < 8; ++k) {
        uint2 v = fth2[(size_t)srck[k] * 64 + lane];
        ftk[k].x = h2f((unsigned short)(v.x & 0xffff));
        ftk[k].y = h2f((unsigned short)(v.x >> 16));
        ftk[k].z = h2f((unsigned short)(v.y & 0xffff));
        ftk[k].w = h2f((unsigned short)(v.y >> 16));
    }
    const float erv = er[(size_t)n * 8 + h];
    float e[8];
#pragma unroll
    for (int k = 0; k < 8; ++k) {
        float ev = el[(size_t)srck[k] * 8 + h] + erv;
        e[k] = ev > 0.f ? ev : NEG_SLOPE * ev;
    }

    // --- softmax over k (redundant across the 8 lanes of each h-group) ---
    float m = e[0];
#pragma unroll
    for (int k = 1; k < 8; ++k) m = fmaxf(m, e[k]);
    float sum = 0.f;
#pragma unroll
    for (int k = 0; k < 8; ++k) {
        e[k] = __expf(e[k] - m);
        sum += e[k];
    }
    const float inv = 1.0f / sum;

    float4 acc = make_float4(0.f, 0.f, 0.f, 0.f);
#pragma unroll
    for (int k = 0; k < 8; ++k) {
        float a = e[k] * inv;
        acc.x += a * ftk[k].x;
        acc.y += a * ftk[k].y;
        acc.z += a * ftk[k].z;
        acc.w += a * ftk[k].w;
    }
    acc.x = acc.x > 0.f ? acc.x : __expf(acc.x) - 1.f;
    acc.y = acc.y > 0.f ? acc.y : __expf(acc.y) - 1.f;
    acc.z = acc.z > 0.f ? acc.z : __expf(acc.z) - 1.f;
    acc.w = acc.w > 0.f ? acc.w : __expf(acc.w) - 1.f;
    out4[(size_t)n * 64 + lane] = acc;
}

// ---------------------------------------------------------------------------
extern "C" void kernel_launch(void* const* d_in, const int* in_sizes, int n_in,
                              void* d_out, int out_size, void* d_ws, size_t ws_size,
                              hipStream_t stream) {
    const float* feat = (const float*)d_in[0];   // [N,256] fp32
    const int* nbr    = (const int*)d_in[1];     // [N,64] int32
    const float* p    = (const float*)d_in[2];   // [1,256]
    const float* W    = (const float*)d_in[3];   // [256,256]
    const float* al   = (const float*)d_in[4];   // [1,8,32]
    const float* ar   = (const float*)d_in[5];   // [1,8,32]
    float* out = (float*)d_out;                  // [N,8,32] fp32

    const int N = in_sizes[0] / 256;

    // ws: y[N] f32 | Wtp[64K] fp16 | el[N*8] f32 | er[N*8] f32 | fth[N*256] fp16
    // = 0.2 + 0.131 + 1.6 + 1.6 + 25.6 MB = 29.1 MB
    float* y = (float*)d_ws;
    unsigned short* Wtp = (unsigned short*)(y + N);
    float* el = (float*)(Wtp + 256 * 256);
    float* er = el + (size_t)N * 8;
    unsigned short* fth = (unsigned short*)(er + (size_t)N * 8);

    k_prepw<<<256, 256, 0, stream>>>(W, Wtp);
    k_fused<<<(N + 31) / 32, 256, 0, stream>>>((const float4*)feat, (const float4*)p,
                                               Wtp, (const float4*)al, (const float4*)ar,
                                               y, fth, el, er, N);
    k_aggr<<<(N + 3) / 4, 256, 0, stream>>>(nbr, y, (const uint2*)fth, el, er,
                                            (float4*)out, N);
}

// Round 6
// 171.719 us; speedup vs baseline: 1.0356x; 1.0356x over previous
//
#include <hip/hip_runtime.h>
#include <math.h>

#define NEG_SLOPE 0.2f

typedef _Float16 half8 __attribute__((ext_vector_type(8)));
typedef _Float16 half2v __attribute__((ext_vector_type(2)));
typedef float floatx4 __attribute__((ext_vector_type(4)));

__device__ __forceinline__ float dot4f(float4 a, float4 b) {
    return a.x * b.x + a.y * b.y + a.z * b.z + a.w * b.w;
}

static __device__ __forceinline__ unsigned short f2h(float x) {
    _Float16 h = (_Float16)x;               // RNE
    return __builtin_bit_cast(unsigned short, h);
}
static __device__ __forceinline__ float h2f(unsigned short u) {
    _Float16 h = __builtin_bit_cast(_Float16, u);
    return (float)h;
}

// ---------------------------------------------------------------------------
// Kernel 0: build both constant fp16 operand tables in MFMA-B-fragment order.
//  blocks 0..255  : Wtp[cp][kc][cm][j] = fp16(W[kc*8+j][cp*16+cm])
//  blocks 256..271: Mp[kc][t][j] = head-masked al/ar table M[k][t]:
//     t<8 : M[k][t] = (k>>5==t)   ? al[t][k&31]   : 0
//     t>=8: M[k][t] = (k>>5==t-8) ? ar[t-8][k&31] : 0
//  so that el/er = C @ M is a single MFMA chain in k_fused's epilogue.
// ---------------------------------------------------------------------------
__global__ void k_prepw(const float* __restrict__ W,
                        const float* __restrict__ al,
                        const float* __restrict__ ar,
                        unsigned short* __restrict__ Wtp,
                        unsigned short* __restrict__ Mp) {
    const int k = threadIdx.x;      // 256 ks
    if (blockIdx.x < 256) {
        const int c = blockIdx.x;
        float v = W[(size_t)k * 256 + c];
        Wtp[(size_t)(c >> 4) * 4096 + (k >> 3) * 128 + (c & 15) * 8 + (k & 7)] = f2h(v);
    } else {
        const int t = blockIdx.x - 256;   // 0..15
        float v = 0.f;
        if (t < 8) {
            if ((k >> 5) == t) v = al[t * 32 + (k & 31)];
        } else {
            if ((k >> 5) == (t - 8)) v = ar[(t - 8) * 32 + (k & 31)];
        }
        Mp[(k >> 3) * 128 + t * 8 + (k & 7)] = f2h(v);
    }
}

// ---------------------------------------------------------------------------
// Kernel 1 (fused score + GEMM + el/er): block = 256 thr = 4 waves = 32 nodes.
// Phase A: per node y = |feat.p|/||p||, gate, gated fp16 row -> LDS As.
// Phase B: 32x256 @ 256x256 MFMA matmul; wave w owns cols w*64..w*64+63.
// Epilogue: C panel (fp16) -> As (overwrite) + fth (global).
// Phase C: el/er = C @ M via MFMA (waves 0,1 only; 8 MFMA each) — replaces
//   the previous ~250-VALU-op cooperative dot-product phase.
// ---------------------------------------------------------------------------
__global__ __launch_bounds__(256) void k_fused(const float4* __restrict__ feat4,
                                               const float4* __restrict__ p4,
                                               const unsigned short* __restrict__ Wtp,
                                               const unsigned short* __restrict__ Mp,
                                               float* __restrict__ y,
                                               unsigned short* __restrict__ fth,
                                               float* __restrict__ el,
                                               float* __restrict__ er,
                                               int N) {
    __shared__ unsigned short As[32][264];   // 32 rows x 256 halves (+pad)
    const int lane = threadIdx.x & 63;
    const int w = threadIdx.x >> 6;          // wave 0..3
    const int l16 = lane & 15, quad = lane >> 4;
    const int nb = blockIdx.x * 32;

    const float4 p = p4[lane];
    float pp = dot4f(p, p);
#pragma unroll
    for (int off = 32; off; off >>= 1) pp += __shfl_xor(pp, off, 64);
    const float rnorm = 1.0f / sqrtf(pp);

    // ---- phase A: 8 nodes per wave ----
#pragma unroll
    for (int j = 0; j < 8; ++j) {
        const int m = w * 8 + j;
        int n = nb + m;
        const bool valid = n < N;
        if (!valid) n = N - 1;
        float4 f = feat4[(size_t)n * 64 + lane];
        float dp = dot4f(f, p);
#pragma unroll
        for (int off = 32; off; off >>= 1) dp += __shfl_xor(dp, off, 64);
        float yv = fabsf(dp) * rnorm;
        if (lane == 0 && valid) y[n] = yv;
        float g = 2.0f / (1.0f + __expf(-yv));
        ushort4 u;
        u.x = f2h(g * f.x);
        u.y = f2h(g * f.y);
        u.z = f2h(g * f.z);
        u.w = f2h(g * f.w);
        *(ushort4*)&As[m][lane * 4] = u;
    }
    __syncthreads();

    // ---- phase B: 2 m-tiles x 4 col-tiles per wave ----
    floatx4 acc[2][4];
#pragma unroll
    for (int mt = 0; mt < 2; ++mt)
#pragma unroll
        for (int ct = 0; ct < 4; ++ct) acc[mt][ct] = (floatx4){0.f, 0.f, 0.f, 0.f};

    const unsigned short* bbase = Wtp + (size_t)(w * 4) * 4096 + quad * 128 + l16 * 8;

    for (int ks = 0; ks < 256; ks += 32) {
        half8 a0 = *(const half8*)&As[l16][ks + quad * 8];
        half8 a1 = *(const half8*)&As[16 + l16][ks + quad * 8];
        const unsigned short* bk = bbase + (ks >> 3) * 128;
        half8 b0 = *(const half8*)(bk);
        half8 b1 = *(const half8*)(bk + 4096);
        half8 b2 = *(const half8*)(bk + 8192);
        half8 b3 = *(const half8*)(bk + 12288);
        acc[0][0] = __builtin_amdgcn_mfma_f32_16x16x32_f16(a0, b0, acc[0][0], 0, 0, 0);
        acc[0][1] = __builtin_amdgcn_mfma_f32_16x16x32_f16(a0, b1, acc[0][1], 0, 0, 0);
        acc[0][2] = __builtin_amdgcn_mfma_f32_16x16x32_f16(a0, b2, acc[0][2], 0, 0, 0);
        acc[0][3] = __builtin_amdgcn_mfma_f32_16x16x32_f16(a0, b3, acc[0][3], 0, 0, 0);
        acc[1][0] = __builtin_amdgcn_mfma_f32_16x16x32_f16(a1, b0, acc[1][0], 0, 0, 0);
        acc[1][1] = __builtin_amdgcn_mfma_f32_16x16x32_f16(a1, b1, acc[1][1], 0, 0, 0);
        acc[1][2] = __builtin_amdgcn_mfma_f32_16x16x32_f16(a1, b2, acc[1][2], 0, 0, 0);
        acc[1][3] = __builtin_amdgcn_mfma_f32_16x16x32_f16(a1, b3, acc[1][3], 0, 0, 0);
    }

    // ---- epilogue: C panel -> As (fp16) + fth (global) ----
    __syncthreads();   // all A-frag reads done before overwrite
#pragma unroll
    for (int mt = 0; mt < 2; ++mt)
#pragma unroll
        for (int ct = 0; ct < 4; ++ct)
#pragma unroll
            for (int i = 0; i < 4; ++i) {
                int row = mt * 16 + quad * 4 + i;
                int col = w * 64 + ct * 16 + l16;
                unsigned short h = f2h(acc[mt][ct][i]);
                As[row][col] = h;
                int grow = nb + row;
                if (grow < N) fth[(size_t)grow * 256 + col] = h;
            }
    __syncthreads();

    // ---- phase C: el/er = C @ M via MFMA (waves 0,1; wave w -> rows w*16..) ----
    if (w < 2) {
        floatx4 d = (floatx4){0.f, 0.f, 0.f, 0.f};
        for (int ks = 0; ks < 256; ks += 32) {
            half8 a = *(const half8*)&As[w * 16 + l16][ks + quad * 8];
            half8 b = *(const half8*)(Mp + (ks >> 3) * 128 + quad * 128 + l16 * 8);
            d = __builtin_amdgcn_mfma_f32_16x16x32_f16(a, b, d, 0, 0, 0);
        }
        // D layout: col = l16 (t: 0..7 -> el head, 8..15 -> er head), row = quad*4+i
#pragma unroll
        for (int i = 0; i < 4; ++i) {
            int row = nb + w * 16 + quad * 4 + i;
            if (row < N) {
                if (l16 < 8) el[(size_t)row * 8 + l16] = d[i];
                else         er[(size_t)row * 8 + (l16 - 8)] = d[i];
            }
        }
    }
}

// ---------------------------------------------------------------------------
// Kernel 2: per node — top-8 neighbors by y[src] via ballot radix-select
// (exact 8th-largest; tie -> lowest slot; selected SET is order-invariant
// under the symmetric softmax-sum), gather fp16 ft rows + precomputed el,
// leaky-relu, softmax over k, packed-fp16 weighted sum, elu. One wave per
// node; lane holds o-chunk 4*lane..4*lane+3, h = lane>>3.
// ---------------------------------------------------------------------------
__global__ __launch_bounds__(256) void k_aggr(const int* __restrict__ nbr,
                                              const float* __restrict__ y,
                                              const uint2* __restrict__ fth2,
                                              const float* __restrict__ el,
                                              const float* __restrict__ er,
                                              floatx4* __restrict__ out4,
                                              int N) {
    const int lane = threadIdx.x & 63;
    const int n = blockIdx.x * 4 + (threadIdx.x >> 6);
    if (n >= N) return;
    const int h = lane >> 3;

    const int s = nbr[(size_t)n * 64 + lane];
    const unsigned int key = __float_as_uint(y[s]);   // y >= 0 -> order-monotone

    // --- radix-select exact 8th-largest key (31 ballots; y>=0 so bit31=0) ---
    unsigned int t = 0u;
#pragma unroll
    for (int b = 30; b >= 0; --b) {
        unsigned int cand = t | (1u << b);
        unsigned long long m = __ballot(key >= cand);
        if (__popcll(m) >= 8) t = cand;
    }
    const unsigned long long gtmask = __ballot(key > t);
    const int ngt = __popcll(gtmask);                       // <= 7
    const unsigned long long eqmask = __ballot(key == t);
    const unsigned long long below = (1ull << lane) - 1ull;
    const int eqrank = __popcll(eqmask & below);
    const bool in8 = (key > t) | ((key == t) & (eqrank < 8 - ngt));
    unsigned long long selmask = __ballot(in8);             // exactly 8 bits

    int srck[8];
#pragma unroll
    for (int k = 0; k < 8; ++k) {
        int l = __ffsll((long long)selmask) - 1;
        srck[k] = __shfl(s, l, 64);
        selmask &= selmask - 1ull;
    }

    // --- gather fp16 ft rows (8B/lane, coalesced across wave) ---
    uint2 vk[8];
#pragma unroll
    for (int k = 0; k < 8; ++k) vk[k] = fth2[(size_t)srck[k] * 64 + lane];

    const float erv = er[(size_t)n * 8 + h];
    float e[8];
#pragma unroll
    for (int k = 0; k < 8; ++k) {
        float ev = el[(size_t)srck[k] * 8 + h] + erv;
        e[k] = ev > 0.f ? ev : NEG_SLOPE * ev;
    }

    // --- softmax over k (redundant across the 8 lanes of each h-group) ---
    float m = e[0];
#pragma unroll
    for (int k = 1; k < 8; ++k) m = fmaxf(m, e[k]);
    float sum = 0.f;
#pragma unroll
    for (int k = 0; k < 8; ++k) {
        e[k] = __expf(e[k] - m);
        sum += e[k];
    }
    const float inv = 1.0f / sum;

    // --- packed-fp16 weighted sum (convex combo -> fp16 accumulate safe) ---
    half2v acc0 = (half2v){(_Float16)0, (_Float16)0};
    half2v acc1 = acc0;
#pragma unroll
    for (int k = 0; k < 8; ++k) {
        _Float16 ah = (_Float16)(e[k] * inv);
        half2v a2 = {ah, ah};
        acc0 += a2 * __builtin_bit_cast(half2v, vk[k].x);
        acc1 += a2 * __builtin_bit_cast(half2v, vk[k].y);
    }
    floatx4 r;
    r[0] = (float)acc0[0];
    r[1] = (float)acc0[1];
    r[2] = (float)acc1[0];
    r[3] = (float)acc1[1];
    r[0] = r[0] > 0.f ? r[0] : __expf(r[0]) - 1.f;
    r[1] = r[1] > 0.f ? r[1] : __expf(r[1]) - 1.f;
    r[2] = r[2] > 0.f ? r[2] : __expf(r[2]) - 1.f;
    r[3] = r[3] > 0.f ? r[3] : __expf(r[3]) - 1.f;
    __builtin_nontemporal_store(r, &out4[(size_t)n * 64 + lane]);
}

// ---------------------------------------------------------------------------
extern "C" void kernel_launch(void* const* d_in, const int* in_sizes, int n_in,
                              void* d_out, int out_size, void* d_ws, size_t ws_size,
                              hipStream_t stream) {
    const float* feat = (const float*)d_in[0];   // [N,256] fp32
    const int* nbr    = (const int*)d_in[1];     // [N,64] int32
    const float* p    = (const float*)d_in[2];   // [1,256]
    const float* W    = (const float*)d_in[3];   // [256,256]
    const float* al   = (const float*)d_in[4];   // [1,8,32]
    const float* ar   = (const float*)d_in[5];   // [1,8,32]

    const int N = in_sizes[0] / 256;

    // ws: y[N] | Wtp[64K fp16] | Mp[4K fp16] | el[8N] | er[8N] | fth[256N fp16]
    float* y = (float*)d_ws;
    unsigned short* Wtp = (unsigned short*)(y + N);
    unsigned short* Mp  = Wtp + 256 * 256;
    float* el = (float*)(Mp + 32 * 128);
    float* er = el + (size_t)N * 8;
    unsigned short* fth = (unsigned short*)(er + (size_t)N * 8);

    k_prepw<<<272, 256, 0, stream>>>(W, al, ar, Wtp, Mp);
    k_fused<<<(N + 31) / 32, 256, 0, stream>>>((const float4*)feat, (const float4*)p,
                                               Wtp, Mp, y, fth, el, er, N);
    k_aggr<<<(N + 3) / 4, 256, 0, stream>>>(nbr, y, (const uint2*)fth, el, er,
                                            (floatx4*)d_out, N);
}